// Round 2
// baseline (997.176 us; speedup 1.0000x reference)
//
#include <hip/hip_runtime.h>
#include <hip/hip_bf16.h>
#include <math.h>

typedef __bf16 bf16x8 __attribute__((ext_vector_type(8)));
typedef float floatx4 __attribute__((ext_vector_type(4)));
typedef unsigned short ushort8 __attribute__((ext_vector_type(8)));
typedef unsigned short ushort4v __attribute__((ext_vector_type(4)));

__device__ __forceinline__ unsigned short f2bs(float f){
  union { float f; unsigned u; } v; v.f = f;
  unsigned r = v.u + 0x7fffu + ((v.u >> 16) & 1u);
  return (unsigned short)(r >> 16);
}

__device__ __forceinline__ void gl_lds16(const void* g, void* l){
  __builtin_amdgcn_global_load_lds(
      (const __attribute__((address_space(1))) void*)g,
      (__attribute__((address_space(3))) void*)l,
      16, 0, 0);
}

// ---------------- elementwise convert x -> bf16 ----------------
__global__ __launch_bounds__(256) void cvt_x(const float* __restrict__ x,
                                             unsigned short* __restrict__ o){
  const int i = (blockIdx.x*256 + threadIdx.x)*4;
  const float4 v = *(const float4*)(x + i);
  ushort4v u = { f2bs(v.x), f2bs(v.y), f2bs(v.z), f2bs(v.w) };
  *(ushort4v*)(o + i) = u;
}

// ---------------- generic fp32 [R][C] -> bf16 [C][R] transpose ----------------
__global__ __launch_bounds__(256) void transpose_pack(const float* __restrict__ src,
                                                      unsigned short* __restrict__ dst,
                                                      int R, int C){
  __shared__ float tile[32][65];
  const int r0 = blockIdx.y*32, c0 = blockIdx.x*64;
  const int t = threadIdx.x;
  {
    const int r = t >> 3, cc = (t & 7)*8;
    const float* p = src + (size_t)(r0+r)*C + c0 + cc;
    const float4 v0 = *(const float4*)p;
    const float4 v1 = *(const float4*)(p+4);
    tile[r][cc+0]=v0.x; tile[r][cc+1]=v0.y; tile[r][cc+2]=v0.z; tile[r][cc+3]=v0.w;
    tile[r][cc+4]=v1.x; tile[r][cc+5]=v1.y; tile[r][cc+6]=v1.z; tile[r][cc+7]=v1.w;
  }
  __syncthreads();
  const int f = t >> 2, rr = (t & 3)*8;
  ushort8 u;
  #pragma unroll
  for (int j=0;j<8;j++) u[j] = f2bs(tile[rr+j][f]);
  *(ushort8*)(dst + (size_t)(c0+f)*R + r0 + rr) = u;
}

// ---------------- pack wq/wk/wv [H,D,HD] -> Wqkv_t [3072][1024] bf16 + bias ----------------
__global__ __launch_bounds__(256) void pack_qkv(const float* __restrict__ wq,
                                                const float* __restrict__ wk,
                                                const float* __restrict__ wv,
                                                const float* __restrict__ bq,
                                                const float* __restrict__ bk,
                                                const float* __restrict__ bv,
                                                unsigned short* __restrict__ Wt,
                                                float* __restrict__ Bc){
  __shared__ float tile[32][65];
  const int dt = blockIdx.x, h = blockIdx.y, sel = blockIdx.z;
  const float* src = (sel==0 ? wq : (sel==1 ? wk : wv)) + (size_t)h*65536;
  const int t = threadIdx.x, d0 = dt*32;
  {
    const int r = t >> 3, cc = (t & 7)*8;
    const float* p = src + (size_t)(d0+r)*64 + cc;
    const float4 v0 = *(const float4*)p;
    const float4 v1 = *(const float4*)(p+4);
    tile[r][cc+0]=v0.x; tile[r][cc+1]=v0.y; tile[r][cc+2]=v0.z; tile[r][cc+3]=v0.w;
    tile[r][cc+4]=v1.x; tile[r][cc+5]=v1.y; tile[r][cc+6]=v1.z; tile[r][cc+7]=v1.w;
  }
  __syncthreads();
  const int f = t >> 2, rr = (t & 3)*8;
  ushort8 u;
  #pragma unroll
  for (int j=0;j<8;j++) u[j] = f2bs(tile[rr+j][f]);
  const size_t n = (size_t)sel*1024 + h*64 + f;
  *(ushort8*)(Wt + n*1024 + d0 + rr) = u;
  if (dt==0 && t<64){
    const float* bs = (sel==0 ? bq : (sel==1 ? bk : bv)) + h*64;
    Bc[sel*1024 + h*64 + t] = bs[t];
  }
}

// ---------------- m97-style bf16 GEMM: C[M,N] = A[M,K] * Bt[N,K]^T + bias ----------------
// MODE 1: fp32 out0.  MODE 2: exact-gelu -> bf16 out0.  MODE 3: fused QKV epilogue.
template<int MODE>
__global__ __launch_bounds__(256) void gemm_bt(const unsigned short* __restrict__ A,
                                               const unsigned short* __restrict__ Bt,
                                               const float* __restrict__ bias,
                                               void* __restrict__ out0,
                                               void* __restrict__ out1,
                                               void* __restrict__ out2,
                                               int M, int N, int K){
  __shared__ __align__(16) unsigned short As[128*32];
  __shared__ __align__(16) unsigned short Bs[128*32];
  const int tid = threadIdx.x;
  const int wave = tid >> 6, lane = tid & 63;
  const int quad = lane >> 4, l15 = lane & 15;
  const int m0 = blockIdx.y << 7, n0 = blockIdx.x << 7;
  const int wr = (wave >> 1) << 6, wc = (wave & 1) << 6;

  floatx4 acc[4][4];
  #pragma unroll
  for (int i=0;i<4;i++)
    #pragma unroll
    for (int j=0;j<4;j++) acc[i][j] = (floatx4)0.0f;

  const int slot0 = wave*128 + lane;
  const int r0s = slot0 >> 2, c0s = (slot0 & 3)*8;
  const int slot1 = slot0 + 64;
  const int r1s = slot1 >> 2, c1s = (slot1 & 3)*8;
  const unsigned short* pa0 = A  + (size_t)(m0 + r0s)*K + c0s;
  const unsigned short* pa1 = A  + (size_t)(m0 + r1s)*K + c1s;
  const unsigned short* pb0 = Bt + (size_t)(n0 + r0s)*K + c0s;
  const unsigned short* pb1 = Bt + (size_t)(n0 + r1s)*K + c1s;

  for (int k0 = 0; k0 < K; k0 += 32){
    gl_lds16(pa0 + k0, As + wave*1024);
    gl_lds16(pa1 + k0, As + wave*1024 + 512);
    gl_lds16(pb0 + k0, Bs + wave*1024);
    gl_lds16(pb1 + k0, Bs + wave*1024 + 512);
    __syncthreads();
    bf16x8 af[4], bfv[4];
    #pragma unroll
    for (int t=0;t<4;t++){
      af[t]  = *(const bf16x8*)(As + (wr + t*16 + l15)*32 + quad*8);
      bfv[t] = *(const bf16x8*)(Bs + (wc + t*16 + l15)*32 + quad*8);
    }
    #pragma unroll
    for (int i=0;i<4;i++)
      #pragma unroll
      for (int j=0;j<4;j++)
        acc[i][j] = __builtin_amdgcn_mfma_f32_16x16x32_bf16(af[i], bfv[j], acc[i][j], 0,0,0);
    __syncthreads();
  }

  #pragma unroll
  for (int i=0;i<4;i++){
    #pragma unroll
    for (int j=0;j<4;j++){
      const int col = n0 + wc + j*16 + l15;
      const float bsv = bias[col];
      #pragma unroll
      for (int r=0;r<4;r++){
        const int row = m0 + wr + i*16 + quad*4 + r;
        const float v = acc[i][j][r] + bsv;
        if (MODE == 1){
          ((float*)out0)[(size_t)row*N + col] = v;
        } else if (MODE == 2){
          const float gl = 0.5f*v*(1.0f + erff(v*0.70710678118654752f));
          ((unsigned short*)out0)[(size_t)row*N + col] = f2bs(gl);
        } else { // MODE 3: QKV
          if (col < 1024){
            // fold 1/8 (head scale) and log2(e) (softmax uses exp2) into Q
            ((unsigned short*)out0)[(size_t)row*1024 + col] = f2bs(v*0.18033688011112042f);
          } else if (col < 2048){
            ((unsigned short*)out1)[(size_t)row*1024 + (col-1024)] = f2bs(v);
          } else {
            const int n = col - 2048, h = n >> 6, fidx = n & 63;
            const int b = row >> 11, s = row & 2047;
            ((unsigned short*)out2)[(size_t)(((b<<4) + h)*64 + fidx)*2048 + s] = f2bs(v);
          }
        }
      }
    }
  }
}

// ---------------- causal flash attention, register-resident K/V ----------------
// Q [8192][1024] bf16 (pre-scaled by log2e/8), K [8192][1024] bf16,
// Vt [64][64][2048] bf16, O [8192][1024] bf16.
// Block = (qt, bh): 64 q-rows; each wave owns 16 q-rows and runs the whole
// KV sweep independently: K/V fragments loaded global->VGPR (16B contiguous
// per lane, no layout transform), NO __syncthreads anywhere. Only the P
// C-layout -> A-layout transform round-trips wave-private LDS (in-order DS).
__global__ __launch_bounds__(256) void attn(const unsigned short* __restrict__ Q,
                                            const unsigned short* __restrict__ Kg,
                                            const unsigned short* __restrict__ Vt,
                                            unsigned short* __restrict__ O){
  __shared__ __align__(16) unsigned short Ps[4][16*88]; // stride 88: 16B-aligned rows, conflict-benign

  const int qt = 31 - blockIdx.x;            // longest blocks launch first
  const int bh = blockIdx.y;
  const int b = bh >> 4, h = bh & 15;
  const int tid = threadIdx.x, wave = tid >> 6, lane = tid & 63;
  const int quad = lane >> 4, l15 = lane & 15;

  // Q fragment (A-layout): rows = qt*64 + wave*16 + l15
  const size_t qoff = (size_t)((b<<11) + (qt<<6) + (wave<<4) + l15)*1024 + (h<<6);
  bf16x8 qf[2];
  qf[0] = *(const bf16x8*)(Q + qoff + quad*8);
  qf[1] = *(const bf16x8*)(Q + qoff + 32 + quad*8);

  floatx4 oa[4];
  #pragma unroll
  for (int i=0;i<4;i++) oa[i] = (floatx4)0.0f;
  float mi[4] = {-1e30f,-1e30f,-1e30f,-1e30f};
  float li[4] = {0.0f,0.0f,0.0f,0.0f};

  const unsigned short* Kbh = Kg + ((size_t)(b<<11))*1024 + (h<<6);
  const unsigned short* Vbh = Vt + (size_t)bh*64*2048;
  unsigned short* Pw = &Ps[wave][0];

  for (int kt = 0; kt <= qt; ++kt){
    // K fragments (B-layout): B[k=quad*8+j][n=l15] = K[kt*64+tj*16+l15][ks*32+quad*8+j]
    const unsigned short* Kt = Kbh + (size_t)(kt<<6)*1024;
    bf16x8 kf[4][2], vfr[4][2];
    #pragma unroll
    for (int tj=0;tj<4;tj++)
      #pragma unroll
      for (int ks=0;ks<2;ks++)
        kf[tj][ks] = *(const bf16x8*)(Kt + (size_t)(tj*16 + l15)*1024 + (ks*4+quad)*8);
    // V fragments (B-layout): B[k=kv][n=hd] = Vt[hd=tn*16+l15][kt*64+ks*32+quad*8+j]
    #pragma unroll
    for (int tn=0;tn<4;tn++)
      #pragma unroll
      for (int ks=0;ks<2;ks++)
        vfr[tn][ks] = *(const bf16x8*)(Vbh + (size_t)(tn*16 + l15)*2048 + (kt<<6) + ks*32 + quad*8);

    // S = Q' K^T  (16 q-rows x 64 kv), already in log2 units
    floatx4 sa[4];
    #pragma unroll
    for (int tj=0;tj<4;tj++){
      sa[tj] = (floatx4)0.0f;
      #pragma unroll
      for (int ks=0;ks<2;ks++)
        sa[tj] = __builtin_amdgcn_mfma_f32_16x16x32_bf16(qf[ks], kf[tj][ks], sa[tj], 0,0,0);
    }

    if (kt == qt){
      #pragma unroll
      for (int tj=0;tj<4;tj++){
        const int colL = tj*16 + l15;
        #pragma unroll
        for (int r=0;r<4;r++){
          const int rowL = (wave<<4) + quad*4 + r;
          if (colL > rowL) sa[tj][r] = -1e30f;
        }
      }
    }

    // online softmax in exp2 domain; row stats per (quad,r), reduce over l15
    #pragma unroll
    for (int r=0;r<4;r++){
      float mx = fmaxf(fmaxf(sa[0][r], sa[1][r]), fmaxf(sa[2][r], sa[3][r]));
      #pragma unroll
      for (int d=1; d<16; d<<=1) mx = fmaxf(mx, __shfl_xor(mx, d, 64));
      const float mn = fmaxf(mi[r], mx);
      const float al = __builtin_amdgcn_exp2f(mi[r] - mn);
      float rsum = 0.0f;
      #pragma unroll
      for (int tj=0;tj<4;tj++){
        const float p = __builtin_amdgcn_exp2f(sa[tj][r] - mn);
        sa[tj][r] = p;
        rsum += p;
      }
      #pragma unroll
      for (int d=1; d<16; d<<=1) rsum += __shfl_xor(rsum, d, 64);
      li[r] = li[r]*al + rsum;
      mi[r] = mn;
      #pragma unroll
      for (int tn=0;tn<4;tn++) oa[tn][r] *= al;
    }

    // P (C-layout) -> wave-private LDS -> A-layout fragments (no barrier needed)
    #pragma unroll
    for (int tj=0;tj<4;tj++)
      #pragma unroll
      for (int r=0;r<4;r++)
        Pw[(quad*4+r)*88 + tj*16 + l15] = f2bs(sa[tj][r]);

    #pragma unroll
    for (int ks2=0;ks2<2;ks2++){
      const bf16x8 pf = *(const bf16x8*)(Pw + l15*88 + ks2*32 + quad*8);
      #pragma unroll
      for (int tn=0;tn<4;tn++)
        oa[tn] = __builtin_amdgcn_mfma_f32_16x16x32_bf16(pf, vfr[tn][ks2], oa[tn], 0,0,0);
    }
  }

  #pragma unroll
  for (int tn=0;tn<4;tn++){
    #pragma unroll
    for (int r=0;r<4;r++){
      const int qrow = (qt<<6) + (wave<<4) + quad*4 + r;
      const float v = oa[tn][r] / li[r];
      O[(size_t)((b<<11) + qrow)*1024 + (h<<6) + tn*16 + l15] = f2bs(v);
    }
  }
}

// ---------------- residual + LayerNorm (one row per block) ----------------
__global__ __launch_bounds__(256) void ln_res(const float* __restrict__ a,
                                              const float* __restrict__ bsrc,
                                              const float* __restrict__ g,
                                              const float* __restrict__ be,
                                              float* __restrict__ of,
                                              unsigned short* __restrict__ ob){
  __shared__ float red1[4], red2[4];
  const int row = blockIdx.x, t = threadIdx.x;
  const int wave = t >> 6, lane = t & 63;
  const float4 va = *(const float4*)(a + (size_t)row*1024 + t*4);
  const float4 vb = *(const float4*)(bsrc + (size_t)row*1024 + t*4);
  float xs[4] = {va.x+vb.x, va.y+vb.y, va.z+vb.z, va.w+vb.w};
  float s = xs[0]+xs[1]+xs[2]+xs[3];
  #pragma unroll
  for (int d=1; d<64; d<<=1) s += __shfl_xor(s, d, 64);
  if (lane==0) red1[wave] = s;
  __syncthreads();
  const float mean = (red1[0]+red1[1]+red1[2]+red1[3]) * (1.0f/1024.0f);
  float vsum = 0.0f;
  #pragma unroll
  for (int i=0;i<4;i++){ const float d = xs[i]-mean; vsum += d*d; }
  #pragma unroll
  for (int d=1; d<64; d<<=1) vsum += __shfl_xor(vsum, d, 64);
  if (lane==0) red2[wave] = vsum;
  __syncthreads();
  const float var = (red2[0]+red2[1]+red2[2]+red2[3]) * (1.0f/1024.0f);
  const float rs = rsqrtf(var + 1e-5f);
  const float4 gg = *(const float4*)(g + t*4);
  const float4 bb = *(const float4*)(be + t*4);
  float y[4];
  y[0] = (xs[0]-mean)*rs*gg.x + bb.x;
  y[1] = (xs[1]-mean)*rs*gg.y + bb.y;
  y[2] = (xs[2]-mean)*rs*gg.z + bb.z;
  y[3] = (xs[3]-mean)*rs*gg.w + bb.w;
  if (of){
    float4 o4; o4.x=y[0]; o4.y=y[1]; o4.z=y[2]; o4.w=y[3];
    *(float4*)(of + (size_t)row*1024 + t*4) = o4;
  }
  if (ob){
    ushort4v u = { f2bs(y[0]), f2bs(y[1]), f2bs(y[2]), f2bs(y[3]) };
    *(ushort4v*)(ob + (size_t)row*1024 + t*4) = u;
  }
}

extern "C" void kernel_launch(void* const* d_in, const int* in_sizes, int n_in,
                              void* d_out, int out_size, void* d_ws, size_t ws_size,
                              hipStream_t stream){
  (void)in_sizes; (void)n_in; (void)out_size; (void)ws_size;
  const float* x  = (const float*)d_in[0];
  const float* wq = (const float*)d_in[1];
  const float* bq = (const float*)d_in[2];
  const float* wk = (const float*)d_in[3];
  const float* bk = (const float*)d_in[4];
  const float* wv = (const float*)d_in[5];
  const float* bv = (const float*)d_in[6];
  const float* wo = (const float*)d_in[7];
  const float* bo = (const float*)d_in[8];
  const float* w1 = (const float*)d_in[9];
  const float* b1 = (const float*)d_in[10];
  const float* w2 = (const float*)d_in[11];
  const float* b2 = (const float*)d_in[12];
  const float* g1 = (const float*)d_in[13];
  const float* be1= (const float*)d_in[14];
  const float* g2 = (const float*)d_in[15];
  const float* be2= (const float*)d_in[16];
  float* out = (float*)d_out;

  char* ws = (char*)d_ws;
  size_t off = 0;
  auto take = [&](size_t bytes)->char*{
    char* p = ws + off; off += (bytes + 255) & ~(size_t)255; return p;
  };
  unsigned short* Xb  = (unsigned short*)take(8192UL*1024*2);
  unsigned short* Qb  = (unsigned short*)take(8192UL*1024*2);
  unsigned short* Kb  = (unsigned short*)take(8192UL*1024*2);
  unsigned short* Vtb = (unsigned short*)take(8192UL*1024*2);
  unsigned short* Ob  = (unsigned short*)take(8192UL*1024*2);
  unsigned short* Midb= Qb;                    // alias: spans Qb..Ob (64 MB), dead by FFN1
  unsigned short* Wqkv= (unsigned short*)take(3072UL*1024*2);
  float*          Bqkv= (float*)take(3072UL*4);
  unsigned short* Wot = (unsigned short*)take(1024UL*1024*2);
  unsigned short* W1t = (unsigned short*)take(4096UL*1024*2);
  unsigned short* W2t = (unsigned short*)take(1024UL*4096*2);
  float*          C1  = (float*)take(8192UL*1024*4);
  float*          Ff  = C1;                    // alias: attn-proj dead after LN1
  float*          Hf  = (float*)take(8192UL*1024*4);
  unsigned short* Hb  = (unsigned short*)take(8192UL*1024*2);

  // 1. pack inputs/weights to bf16 MFMA layouts
  cvt_x<<<8192, 256, 0, stream>>>(x, Xb);
  pack_qkv<<<dim3(32,16,3), 256, 0, stream>>>(wq, wk, wv, bq, bk, bv, Wqkv, Bqkv);
  transpose_pack<<<dim3(16,32),  256, 0, stream>>>(wo, Wot, 1024, 1024);
  transpose_pack<<<dim3(64,32),  256, 0, stream>>>(w1, W1t, 1024, 4096);
  transpose_pack<<<dim3(16,128), 256, 0, stream>>>(w2, W2t, 4096, 1024);

  // 2. fused QKV projection (Q pre-scaled log2e/8, V stored transposed)
  gemm_bt<3><<<dim3(24,64), 256, 0, stream>>>(Xb, Wqkv, Bqkv, Qb, Kb, Vtb, 8192, 3072, 1024);

  // 3. causal flash attention (barrier-free, register-resident K/V)
  attn<<<dim3(32,64), 256, 0, stream>>>(Qb, Kb, Vtb, Ob);

  // 4. output projection (fp32) then residual + LN1 -> h (fp32 + bf16)
  gemm_bt<1><<<dim3(8,64), 256, 0, stream>>>(Ob, Wot, bo, C1, nullptr, nullptr, 8192, 1024, 1024);
  ln_res<<<8192, 256, 0, stream>>>(x, C1, g1, be1, Hf, Hb);

  // 5. FFN: gelu(h@w1+b1)@w2+b2, then residual + LN2 -> out
  gemm_bt<2><<<dim3(32,64), 256, 0, stream>>>(Hb, W1t, b1, Midb, nullptr, nullptr, 8192, 4096, 1024);
  gemm_bt<1><<<dim3(8,64), 256, 0, stream>>>(Midb, W2t, b2, Ff, nullptr, nullptr, 8192, 1024, 4096);
  ln_res<<<8192, 256, 0, stream>>>(Hf, Ff, g2, be2, out, nullptr);
}

// Round 3
// 661.962 us; speedup vs baseline: 1.5064x; 1.5064x over previous
//
#include <hip/hip_runtime.h>
#include <hip/hip_bf16.h>
#include <math.h>

typedef __bf16 bf16x8 __attribute__((ext_vector_type(8)));
typedef float floatx4 __attribute__((ext_vector_type(4)));
typedef unsigned short ushort8 __attribute__((ext_vector_type(8)));
typedef unsigned short ushort4v __attribute__((ext_vector_type(4)));

__device__ __forceinline__ unsigned short f2bs(float f){
  union { float f; unsigned u; } v; v.f = f;
  unsigned r = v.u + 0x7fffu + ((v.u >> 16) & 1u);
  return (unsigned short)(r >> 16);
}

// packed f32x2 -> bf16x2 (RNE)
__device__ __forceinline__ unsigned pk2(float a, float b){
  union { __hip_bfloat162 h; unsigned u; } cv;
  cv.h = __float22bfloat162_rn(make_float2(a, b));
  return cv.u;
}

__device__ __forceinline__ void gl_lds16(const void* g, void* l){
  __builtin_amdgcn_global_load_lds(
      (const __attribute__((address_space(1))) void*)g,
      (__attribute__((address_space(3))) void*)l,
      16, 0, 0);
}

// ---------------- elementwise convert x -> bf16 ----------------
__global__ __launch_bounds__(256) void cvt_x(const float* __restrict__ x,
                                             unsigned short* __restrict__ o){
  const int i = (blockIdx.x*256 + threadIdx.x)*4;
  const float4 v = *(const float4*)(x + i);
  ushort4v u = { f2bs(v.x), f2bs(v.y), f2bs(v.z), f2bs(v.w) };
  *(ushort4v*)(o + i) = u;
}

// ---------------- generic fp32 [R][C] -> bf16 [C][R] transpose ----------------
__global__ __launch_bounds__(256) void transpose_pack(const float* __restrict__ src,
                                                      unsigned short* __restrict__ dst,
                                                      int R, int C){
  __shared__ float tile[32][65];
  const int r0 = blockIdx.y*32, c0 = blockIdx.x*64;
  const int t = threadIdx.x;
  {
    const int r = t >> 3, cc = (t & 7)*8;
    const float* p = src + (size_t)(r0+r)*C + c0 + cc;
    const float4 v0 = *(const float4*)p;
    const float4 v1 = *(const float4*)(p+4);
    tile[r][cc+0]=v0.x; tile[r][cc+1]=v0.y; tile[r][cc+2]=v0.z; tile[r][cc+3]=v0.w;
    tile[r][cc+4]=v1.x; tile[r][cc+5]=v1.y; tile[r][cc+6]=v1.z; tile[r][cc+7]=v1.w;
  }
  __syncthreads();
  const int f = t >> 2, rr = (t & 3)*8;
  ushort8 u;
  #pragma unroll
  for (int j=0;j<8;j++) u[j] = f2bs(tile[rr+j][f]);
  *(ushort8*)(dst + (size_t)(c0+f)*R + r0 + rr) = u;
}

// ---------------- pack wq/wk/wv [H,D,HD] -> Wqkv_t [3072][1024] bf16 + bias ----------------
__global__ __launch_bounds__(256) void pack_qkv(const float* __restrict__ wq,
                                                const float* __restrict__ wk,
                                                const float* __restrict__ wv,
                                                const float* __restrict__ bq,
                                                const float* __restrict__ bk,
                                                const float* __restrict__ bv,
                                                unsigned short* __restrict__ Wt,
                                                float* __restrict__ Bc){
  __shared__ float tile[32][65];
  const int dt = blockIdx.x, h = blockIdx.y, sel = blockIdx.z;
  const float* src = (sel==0 ? wq : (sel==1 ? wk : wv)) + (size_t)h*65536;
  const int t = threadIdx.x, d0 = dt*32;
  {
    const int r = t >> 3, cc = (t & 7)*8;
    const float* p = src + (size_t)(d0+r)*64 + cc;
    const float4 v0 = *(const float4*)p;
    const float4 v1 = *(const float4*)(p+4);
    tile[r][cc+0]=v0.x; tile[r][cc+1]=v0.y; tile[r][cc+2]=v0.z; tile[r][cc+3]=v0.w;
    tile[r][cc+4]=v1.x; tile[r][cc+5]=v1.y; tile[r][cc+6]=v1.z; tile[r][cc+7]=v1.w;
  }
  __syncthreads();
  const int f = t >> 2, rr = (t & 3)*8;
  ushort8 u;
  #pragma unroll
  for (int j=0;j<8;j++) u[j] = f2bs(tile[rr+j][f]);
  const size_t n = (size_t)sel*1024 + h*64 + f;
  *(ushort8*)(Wt + n*1024 + d0 + rr) = u;
  if (dt==0 && t<64){
    const float* bs = (sel==0 ? bq : (sel==1 ? bk : bv)) + h*64;
    Bc[sel*1024 + h*64 + t] = bs[t];
  }
}

// ---------------- m97-style bf16 GEMM: C[M,N] = A[M,K] * Bt[N,K]^T + bias ----------------
// MODE 1: fp32 out0.  MODE 2: exact-gelu -> bf16 out0.  MODE 3: fused QKV epilogue.
template<int MODE>
__global__ __launch_bounds__(256) void gemm_bt(const unsigned short* __restrict__ A,
                                               const unsigned short* __restrict__ Bt,
                                               const float* __restrict__ bias,
                                               void* __restrict__ out0,
                                               void* __restrict__ out1,
                                               void* __restrict__ out2,
                                               int M, int N, int K){
  __shared__ __align__(16) unsigned short As[128*32];
  __shared__ __align__(16) unsigned short Bs[128*32];
  const int tid = threadIdx.x;
  const int wave = tid >> 6, lane = tid & 63;
  const int quad = lane >> 4, l15 = lane & 15;
  const int m0 = blockIdx.y << 7, n0 = blockIdx.x << 7;
  const int wr = (wave >> 1) << 6, wc = (wave & 1) << 6;

  floatx4 acc[4][4];
  #pragma unroll
  for (int i=0;i<4;i++)
    #pragma unroll
    for (int j=0;j<4;j++) acc[i][j] = (floatx4)0.0f;

  const int slot0 = wave*128 + lane;
  const int r0s = slot0 >> 2, c0s = (slot0 & 3)*8;
  const int slot1 = slot0 + 64;
  const int r1s = slot1 >> 2, c1s = (slot1 & 3)*8;
  const unsigned short* pa0 = A  + (size_t)(m0 + r0s)*K + c0s;
  const unsigned short* pa1 = A  + (size_t)(m0 + r1s)*K + c1s;
  const unsigned short* pb0 = Bt + (size_t)(n0 + r0s)*K + c0s;
  const unsigned short* pb1 = Bt + (size_t)(n0 + r1s)*K + c1s;

  for (int k0 = 0; k0 < K; k0 += 32){
    gl_lds16(pa0 + k0, As + wave*1024);
    gl_lds16(pa1 + k0, As + wave*1024 + 512);
    gl_lds16(pb0 + k0, Bs + wave*1024);
    gl_lds16(pb1 + k0, Bs + wave*1024 + 512);
    __syncthreads();
    bf16x8 af[4], bfv[4];
    #pragma unroll
    for (int t=0;t<4;t++){
      af[t]  = *(const bf16x8*)(As + (wr + t*16 + l15)*32 + quad*8);
      bfv[t] = *(const bf16x8*)(Bs + (wc + t*16 + l15)*32 + quad*8);
    }
    #pragma unroll
    for (int i=0;i<4;i++)
      #pragma unroll
      for (int j=0;j<4;j++)
        acc[i][j] = __builtin_amdgcn_mfma_f32_16x16x32_bf16(af[i], bfv[j], acc[i][j], 0,0,0);
    __syncthreads();
  }

  #pragma unroll
  for (int i=0;i<4;i++){
    #pragma unroll
    for (int j=0;j<4;j++){
      const int col = n0 + wc + j*16 + l15;
      const float bsv = bias[col];
      if (MODE == 3 && col >= 2048){
        // V branch: 4 consecutive s per lane -> packed b64 store
        const int n = col - 2048, h = n >> 6, fidx = n & 63;
        const int rowb = m0 + wr + i*16 + quad*4;
        const int b = rowb >> 11, s = rowb & 2047;
        float v0 = acc[i][j][0] + bsv, v1 = acc[i][j][1] + bsv;
        float v2 = acc[i][j][2] + bsv, v3 = acc[i][j][3] + bsv;
        unsigned lo = pk2(v0, v1), hi = pk2(v2, v3);
        uint2 pkd = make_uint2(lo, hi);
        *(uint2*)((unsigned short*)out2 + (size_t)(((b<<4) + h)*64 + fidx)*2048 + s) = pkd;
        continue;
      }
      #pragma unroll
      for (int r=0;r<4;r++){
        const int row = m0 + wr + i*16 + quad*4 + r;
        const float v = acc[i][j][r] + bsv;
        if (MODE == 1){
          ((float*)out0)[(size_t)row*N + col] = v;
        } else if (MODE == 2){
          const float gl = 0.5f*v*(1.0f + erff(v*0.70710678118654752f));
          ((unsigned short*)out0)[(size_t)row*N + col] = f2bs(gl);
        } else { // MODE 3: Q / K branches
          if (col < 1024){
            // fold 1/8 (head scale) and log2(e) (softmax uses exp2) into Q
            ((unsigned short*)out0)[(size_t)row*1024 + col] = f2bs(v*0.18033688011112042f);
          } else {
            ((unsigned short*)out1)[(size_t)row*1024 + (col-1024)] = f2bs(v);
          }
        }
      }
    }
  }
}

// ---------------- causal flash attention, S^T formulation ----------------
// Q [8192][1024] bf16 (pre-scaled by log2e/8), K [8192][1024] bf16,
// Vt [64][64][2048] bf16, O [8192][1024] bf16.
// Block = (qt, bh): 64 q-rows, 4 waves x 16 q-rows. K/V tiles staged in LDS
// (coalesced global_load_lds, shared by all 4 waves). S^T = K.Q^T via
// mfma(kf,qf): each q-row's scores live in ONE lane's registers (col=l15),
// so softmax stats are in-register + 2 cross-quad shuffles; P^T packs to
// 4x ds_write_b64; PV = mfma(vf,pf) gives O^T with packed b64 stores.
__global__ __launch_bounds__(256) void attn(const unsigned short* __restrict__ Q,
                                            const unsigned short* __restrict__ Kg,
                                            const unsigned short* __restrict__ Vt,
                                            unsigned short* __restrict__ O){
  __shared__ __align__(16) unsigned short Ks[64*64];
  __shared__ __align__(16) unsigned short Vs[64*64];
  __shared__ __align__(16) unsigned short PT[4][16*68]; // per-wave P^T: row=q(l15), 64 kv, +4 pad

  const int qt = 31 - blockIdx.x;            // longest blocks first
  const int bh = blockIdx.y;
  const int b = bh >> 4, h = bh & 15;
  const int tid = threadIdx.x, wave = tid >> 6, lane = tid & 63;
  const int quad = lane >> 4, l15 = lane & 15;

  // Q fragment (A/B dual-use layout): rows = qt*64 + wave*16 + l15
  const size_t qoff = (size_t)((b<<11) + (qt<<6) + (wave<<4) + l15)*1024 + (h<<6);
  bf16x8 qf[2];
  qf[0] = *(const bf16x8*)(Q + qoff + quad*8);
  qf[1] = *(const bf16x8*)(Q + qoff + 32 + quad*8);

  floatx4 oa[4];                 // oa[tn][r] = O^T[hd=tn*16+quad*4+r][q=l15]
  #pragma unroll
  for (int i=0;i<4;i++) oa[i] = (floatx4)0.0f;
  float mi = -3e38f, li = 0.0f;  // per q-column (l15), replicated across quads

  const unsigned short* Kbh = Kg + ((size_t)(b<<11))*1024 + (h<<6);
  const unsigned short* Vbh = Vt + (size_t)bh*64*2048;
  unsigned short* Pw = &PT[wave][0];

  const int slot0 = wave*128 + lane;
  const int krow0 = slot0 >> 3, kc0 = (slot0 & 7) ^ (krow0 & 7);
  const int slot1 = slot0 + 64;
  const int krow1 = slot1 >> 3, kc1 = (slot1 & 7) ^ (krow1 & 7);

  for (int kt = 0; kt <= qt; ++kt){
    gl_lds16(Kbh + (size_t)((kt<<6) + krow0)*1024 + kc0*8, Ks + wave*1024);
    gl_lds16(Kbh + (size_t)((kt<<6) + krow1)*1024 + kc1*8, Ks + wave*1024 + 512);
    gl_lds16(Vbh + (size_t)krow0*2048 + (kt<<6) + kc0*8, Vs + wave*1024);
    gl_lds16(Vbh + (size_t)krow1*2048 + (kt<<6) + kc1*8, Vs + wave*1024 + 512);
    __syncthreads();

    // S^T = K . Q^T : sa[tj][r] = S^T[kv=tj*16+quad*4+r][q=l15]  (log2 units)
    floatx4 sa[4];
    #pragma unroll
    for (int tj=0;tj<4;tj++){
      sa[tj] = (floatx4)0.0f;
      #pragma unroll
      for (int ks=0;ks<2;ks++){
        const int n = tj*16 + l15;
        const int c = (ks*4 + quad) ^ (n & 7);
        const bf16x8 kf = *(const bf16x8*)(Ks + n*64 + c*8);
        sa[tj] = __builtin_amdgcn_mfma_f32_16x16x32_bf16(kf, qf[ks], sa[tj], 0,0,0);
      }
    }

    if (kt == qt){
      const int qrow = (wave<<4) + l15;
      #pragma unroll
      for (int tj=0;tj<4;tj++)
        #pragma unroll
        for (int r=0;r<4;r++)
          if (tj*16 + quad*4 + r > qrow) sa[tj][r] = -1e30f;
    }

    // online softmax: column stats fully in-lane, 2 cross-quad shuffles each
    float mx = fmaxf(fmaxf(fmaxf(sa[0][0],sa[0][1]),fmaxf(sa[0][2],sa[0][3])),
                     fmaxf(fmaxf(sa[1][0],sa[1][1]),fmaxf(sa[1][2],sa[1][3])));
    mx = fmaxf(mx, fmaxf(fmaxf(fmaxf(sa[2][0],sa[2][1]),fmaxf(sa[2][2],sa[2][3])),
                         fmaxf(fmaxf(sa[3][0],sa[3][1]),fmaxf(sa[3][2],sa[3][3]))));
    mx = fmaxf(mx, __shfl_xor(mx, 16, 64));
    mx = fmaxf(mx, __shfl_xor(mx, 32, 64));
    const float mn = fmaxf(mi, mx);
    const float al = __builtin_amdgcn_exp2f(mi - mn);
    float rs = 0.0f;
    #pragma unroll
    for (int tj=0;tj<4;tj++)
      #pragma unroll
      for (int r=0;r<4;r++){
        const float p = __builtin_amdgcn_exp2f(sa[tj][r] - mn);
        sa[tj][r] = p;
        rs += p;
      }
    rs += __shfl_xor(rs, 16, 64);
    rs += __shfl_xor(rs, 32, 64);
    li = li*al + rs;
    mi = mn;
    #pragma unroll
    for (int tn=0;tn<4;tn++) oa[tn] *= al;

    // P^T: lane's 4 contiguous kv per tj -> packed ds_write_b64 (bank-uniform)
    #pragma unroll
    for (int tj=0;tj<4;tj++){
      uint2 pkd = make_uint2(pk2(sa[tj][0], sa[tj][1]), pk2(sa[tj][2], sa[tj][3]));
      *(uint2*)(Pw + l15*68 + tj*16 + quad*4) = pkd;
    }

    // O^T += V^T . P^T
    #pragma unroll
    for (int ks2=0;ks2<2;ks2++){
      const bf16x8 pf = *(const bf16x8*)(Pw + l15*68 + ks2*32 + quad*8);
      #pragma unroll
      for (int tn=0;tn<4;tn++){
        const int n2 = tn*16 + l15;
        const int c = (ks2*4 + quad) ^ (n2 & 7);
        const bf16x8 vf = *(const bf16x8*)(Vs + n2*64 + c*8);
        oa[tn] = __builtin_amdgcn_mfma_f32_16x16x32_bf16(vf, pf, oa[tn], 0,0,0);
      }
    }
    __syncthreads();
  }

  // epilogue: per lane 16 O^T values = 4 contiguous hd per tn -> packed b64 stores
  const float inv = 1.0f / li;
  const int qrow = (qt<<6) + (wave<<4) + l15;
  unsigned short* Orow = O + (size_t)((b<<11) + qrow)*1024 + (h<<6);
  #pragma unroll
  for (int tn=0;tn<4;tn++){
    uint2 pkd = make_uint2(pk2(oa[tn][0]*inv, oa[tn][1]*inv),
                           pk2(oa[tn][2]*inv, oa[tn][3]*inv));
    *(uint2*)(Orow + tn*16 + quad*4) = pkd;
  }
}

// ---------------- residual + LayerNorm (one row per block) ----------------
__global__ __launch_bounds__(256) void ln_res(const float* __restrict__ a,
                                              const float* __restrict__ bsrc,
                                              const float* __restrict__ g,
                                              const float* __restrict__ be,
                                              float* __restrict__ of,
                                              unsigned short* __restrict__ ob){
  __shared__ float red1[4], red2[4];
  const int row = blockIdx.x, t = threadIdx.x;
  const int wave = t >> 6, lane = t & 63;
  const float4 va = *(const float4*)(a + (size_t)row*1024 + t*4);
  const float4 vb = *(const float4*)(bsrc + (size_t)row*1024 + t*4);
  float xs[4] = {va.x+vb.x, va.y+vb.y, va.z+vb.z, va.w+vb.w};
  float s = xs[0]+xs[1]+xs[2]+xs[3];
  #pragma unroll
  for (int d=1; d<64; d<<=1) s += __shfl_xor(s, d, 64);
  if (lane==0) red1[wave] = s;
  __syncthreads();
  const float mean = (red1[0]+red1[1]+red1[2]+red1[3]) * (1.0f/1024.0f);
  float vsum = 0.0f;
  #pragma unroll
  for (int i=0;i<4;i++){ const float d = xs[i]-mean; vsum += d*d; }
  #pragma unroll
  for (int d=1; d<64; d<<=1) vsum += __shfl_xor(vsum, d, 64);
  if (lane==0) red2[wave] = vsum;
  __syncthreads();
  const float var = (red2[0]+red2[1]+red2[2]+red2[3]) * (1.0f/1024.0f);
  const float rs = rsqrtf(var + 1e-5f);
  const float4 gg = *(const float4*)(g + t*4);
  const float4 bb = *(const float4*)(be + t*4);
  float y[4];
  y[0] = (xs[0]-mean)*rs*gg.x + bb.x;
  y[1] = (xs[1]-mean)*rs*gg.y + bb.y;
  y[2] = (xs[2]-mean)*rs*gg.z + bb.z;
  y[3] = (xs[3]-mean)*rs*gg.w + bb.w;
  if (of){
    float4 o4; o4.x=y[0]; o4.y=y[1]; o4.z=y[2]; o4.w=y[3];
    *(float4*)(of + (size_t)row*1024 + t*4) = o4;
  }
  if (ob){
    ushort4v u = { f2bs(y[0]), f2bs(y[1]), f2bs(y[2]), f2bs(y[3]) };
    *(ushort4v*)(ob + (size_t)row*1024 + t*4) = u;
  }
}

extern "C" void kernel_launch(void* const* d_in, const int* in_sizes, int n_in,
                              void* d_out, int out_size, void* d_ws, size_t ws_size,
                              hipStream_t stream){
  (void)in_sizes; (void)n_in; (void)out_size; (void)ws_size;
  const float* x  = (const float*)d_in[0];
  const float* wq = (const float*)d_in[1];
  const float* bq = (const float*)d_in[2];
  const float* wk = (const float*)d_in[3];
  const float* bk = (const float*)d_in[4];
  const float* wv = (const float*)d_in[5];
  const float* bv = (const float*)d_in[6];
  const float* wo = (const float*)d_in[7];
  const float* bo = (const float*)d_in[8];
  const float* w1 = (const float*)d_in[9];
  const float* b1 = (const float*)d_in[10];
  const float* w2 = (const float*)d_in[11];
  const float* b2 = (const float*)d_in[12];
  const float* g1 = (const float*)d_in[13];
  const float* be1= (const float*)d_in[14];
  const float* g2 = (const float*)d_in[15];
  const float* be2= (const float*)d_in[16];
  float* out = (float*)d_out;

  char* ws = (char*)d_ws;
  size_t off = 0;
  auto take = [&](size_t bytes)->char*{
    char* p = ws + off; off += (bytes + 255) & ~(size_t)255; return p;
  };
  unsigned short* Xb  = (unsigned short*)take(8192UL*1024*2);
  unsigned short* Qb  = (unsigned short*)take(8192UL*1024*2);
  unsigned short* Kb  = (unsigned short*)take(8192UL*1024*2);
  unsigned short* Vtb = (unsigned short*)take(8192UL*1024*2);
  unsigned short* Ob  = (unsigned short*)take(8192UL*1024*2);
  unsigned short* Midb= Qb;                    // alias: spans Qb..Ob (64 MB), dead by FFN1
  unsigned short* Wqkv= (unsigned short*)take(3072UL*1024*2);
  float*          Bqkv= (float*)take(3072UL*4);
  unsigned short* Wot = (unsigned short*)take(1024UL*1024*2);
  unsigned short* W1t = (unsigned short*)take(4096UL*1024*2);
  unsigned short* W2t = (unsigned short*)take(1024UL*4096*2);
  float*          C1  = (float*)take(8192UL*1024*4);
  float*          Ff  = C1;                    // alias: attn-proj dead after LN1
  float*          Hf  = (float*)take(8192UL*1024*4);
  unsigned short* Hb  = (unsigned short*)take(8192UL*1024*2);

  // 1. pack inputs/weights to bf16 MFMA layouts
  cvt_x<<<8192, 256, 0, stream>>>(x, Xb);
  pack_qkv<<<dim3(32,16,3), 256, 0, stream>>>(wq, wk, wv, bq, bk, bv, Wqkv, Bqkv);
  transpose_pack<<<dim3(16,32),  256, 0, stream>>>(wo, Wot, 1024, 1024);
  transpose_pack<<<dim3(64,32),  256, 0, stream>>>(w1, W1t, 1024, 4096);
  transpose_pack<<<dim3(16,128), 256, 0, stream>>>(w2, W2t, 4096, 1024);

  // 2. fused QKV projection (Q pre-scaled log2e/8, V stored transposed)
  gemm_bt<3><<<dim3(24,64), 256, 0, stream>>>(Xb, Wqkv, Bqkv, Qb, Kb, Vtb, 8192, 3072, 1024);

  // 3. causal flash attention (LDS-staged K/V, S^T formulation)
  attn<<<dim3(32,64), 256, 0, stream>>>(Qb, Kb, Vtb, Ob);

  // 4. output projection (fp32) then residual + LN1 -> h (fp32 + bf16)
  gemm_bt<1><<<dim3(8,64), 256, 0, stream>>>(Ob, Wot, bo, C1, nullptr, nullptr, 8192, 1024, 1024);
  ln_res<<<8192, 256, 0, stream>>>(x, C1, g1, be1, Hf, Hb);

  // 5. FFN: gelu(h@w1+b1)@w2+b2, then residual + LN2 -> out
  gemm_bt<2><<<dim3(32,64), 256, 0, stream>>>(Hb, W1t, b1, Midb, nullptr, nullptr, 8192, 4096, 1024);
  gemm_bt<1><<<dim3(8,64), 256, 0, stream>>>(Midb, W2t, b2, Ff, nullptr, nullptr, 8192, 1024, 4096);
  ln_res<<<8192, 256, 0, stream>>>(Hf, Ff, g2, be2, out, nullptr);
}

// Round 4
// 642.589 us; speedup vs baseline: 1.5518x; 1.0301x over previous
//
#include <hip/hip_runtime.h>
#include <hip/hip_bf16.h>
#include <math.h>

typedef __bf16 bf16x8 __attribute__((ext_vector_type(8)));
typedef float floatx4 __attribute__((ext_vector_type(4)));
typedef unsigned short ushort8 __attribute__((ext_vector_type(8)));
typedef unsigned short ushort4v __attribute__((ext_vector_type(4)));

__device__ __forceinline__ unsigned short f2bs(float f){
  union { float f; unsigned u; } v; v.f = f;
  unsigned r = v.u + 0x7fffu + ((v.u >> 16) & 1u);
  return (unsigned short)(r >> 16);
}

// packed f32x2 -> bf16x2 (RNE)
__device__ __forceinline__ unsigned pk2(float a, float b){
  union { __hip_bfloat162 h; unsigned u; } cv;
  cv.h = __float22bfloat162_rn(make_float2(a, b));
  return cv.u;
}

__device__ __forceinline__ void gl_lds16(const void* g, void* l){
  __builtin_amdgcn_global_load_lds(
      (const __attribute__((address_space(1))) void*)g,
      (__attribute__((address_space(3))) void*)l,
      16, 0, 0);
}

// ---------------- elementwise convert x -> bf16 ----------------
__global__ __launch_bounds__(256) void cvt_x(const float* __restrict__ x,
                                             unsigned short* __restrict__ o){
  const int i = (blockIdx.x*256 + threadIdx.x)*4;
  const float4 v = *(const float4*)(x + i);
  ushort4v u = { f2bs(v.x), f2bs(v.y), f2bs(v.z), f2bs(v.w) };
  *(ushort4v*)(o + i) = u;
}

// ---------------- generic fp32 [R][C] -> bf16 [C][R] transpose ----------------
__global__ __launch_bounds__(256) void transpose_pack(const float* __restrict__ src,
                                                      unsigned short* __restrict__ dst,
                                                      int R, int C){
  __shared__ float tile[32][65];
  const int r0 = blockIdx.y*32, c0 = blockIdx.x*64;
  const int t = threadIdx.x;
  {
    const int r = t >> 3, cc = (t & 7)*8;
    const float* p = src + (size_t)(r0+r)*C + c0 + cc;
    const float4 v0 = *(const float4*)p;
    const float4 v1 = *(const float4*)(p+4);
    tile[r][cc+0]=v0.x; tile[r][cc+1]=v0.y; tile[r][cc+2]=v0.z; tile[r][cc+3]=v0.w;
    tile[r][cc+4]=v1.x; tile[r][cc+5]=v1.y; tile[r][cc+6]=v1.z; tile[r][cc+7]=v1.w;
  }
  __syncthreads();
  const int f = t >> 2, rr = (t & 3)*8;
  ushort8 u;
  #pragma unroll
  for (int j=0;j<8;j++) u[j] = f2bs(tile[rr+j][f]);
  *(ushort8*)(dst + (size_t)(c0+f)*R + r0 + rr) = u;
}

// ---------------- pack wq/wk/wv [H,D,HD] -> Wqkv_t [3072][1024] bf16 + bias ----------------
__global__ __launch_bounds__(256) void pack_qkv(const float* __restrict__ wq,
                                                const float* __restrict__ wk,
                                                const float* __restrict__ wv,
                                                const float* __restrict__ bq,
                                                const float* __restrict__ bk,
                                                const float* __restrict__ bv,
                                                unsigned short* __restrict__ Wt,
                                                float* __restrict__ Bc){
  __shared__ float tile[32][65];
  const int dt = blockIdx.x, h = blockIdx.y, sel = blockIdx.z;
  const float* src = (sel==0 ? wq : (sel==1 ? wk : wv)) + (size_t)h*65536;
  const int t = threadIdx.x, d0 = dt*32;
  {
    const int r = t >> 3, cc = (t & 7)*8;
    const float* p = src + (size_t)(d0+r)*64 + cc;
    const float4 v0 = *(const float4*)p;
    const float4 v1 = *(const float4*)(p+4);
    tile[r][cc+0]=v0.x; tile[r][cc+1]=v0.y; tile[r][cc+2]=v0.z; tile[r][cc+3]=v0.w;
    tile[r][cc+4]=v1.x; tile[r][cc+5]=v1.y; tile[r][cc+6]=v1.z; tile[r][cc+7]=v1.w;
  }
  __syncthreads();
  const int f = t >> 2, rr = (t & 3)*8;
  ushort8 u;
  #pragma unroll
  for (int j=0;j<8;j++) u[j] = f2bs(tile[rr+j][f]);
  const size_t n = (size_t)sel*1024 + h*64 + f;
  *(ushort8*)(Wt + n*1024 + d0 + rr) = u;
  if (dt==0 && t<64){
    const float* bs = (sel==0 ? bq : (sel==1 ? bk : bv)) + h*64;
    Bc[sel*1024 + h*64 + t] = bs[t];
  }
}

// ---------------- m97-style bf16 GEMM: C[M,N] = A[M,K] * Bt[N,K]^T + bias ----------------
// MODE 1: fp32 out0.  MODE 2: exact-gelu -> bf16 out0.  MODE 3: fused QKV epilogue.
template<int MODE>
__global__ __launch_bounds__(256) void gemm_bt(const unsigned short* __restrict__ A,
                                               const unsigned short* __restrict__ Bt,
                                               const float* __restrict__ bias,
                                               void* __restrict__ out0,
                                               void* __restrict__ out1,
                                               void* __restrict__ out2,
                                               int M, int N, int K){
  __shared__ __align__(16) unsigned short As[128*32];
  __shared__ __align__(16) unsigned short Bs[128*32];
  const int tid = threadIdx.x;
  const int wave = tid >> 6, lane = tid & 63;
  const int quad = lane >> 4, l15 = lane & 15;
  const int m0 = blockIdx.y << 7, n0 = blockIdx.x << 7;
  const int wr = (wave >> 1) << 6, wc = (wave & 1) << 6;

  floatx4 acc[4][4];
  #pragma unroll
  for (int i=0;i<4;i++)
    #pragma unroll
    for (int j=0;j<4;j++) acc[i][j] = (floatx4)0.0f;

  const int slot0 = wave*128 + lane;
  const int r0s = slot0 >> 2, c0s = (slot0 & 3)*8;
  const int slot1 = slot0 + 64;
  const int r1s = slot1 >> 2, c1s = (slot1 & 3)*8;
  const unsigned short* pa0 = A  + (size_t)(m0 + r0s)*K + c0s;
  const unsigned short* pa1 = A  + (size_t)(m0 + r1s)*K + c1s;
  const unsigned short* pb0 = Bt + (size_t)(n0 + r0s)*K + c0s;
  const unsigned short* pb1 = Bt + (size_t)(n0 + r1s)*K + c1s;

  for (int k0 = 0; k0 < K; k0 += 32){
    gl_lds16(pa0 + k0, As + wave*1024);
    gl_lds16(pa1 + k0, As + wave*1024 + 512);
    gl_lds16(pb0 + k0, Bs + wave*1024);
    gl_lds16(pb1 + k0, Bs + wave*1024 + 512);
    __syncthreads();
    bf16x8 af[4], bfv[4];
    #pragma unroll
    for (int t=0;t<4;t++){
      af[t]  = *(const bf16x8*)(As + (wr + t*16 + l15)*32 + quad*8);
      bfv[t] = *(const bf16x8*)(Bs + (wc + t*16 + l15)*32 + quad*8);
    }
    #pragma unroll
    for (int i=0;i<4;i++)
      #pragma unroll
      for (int j=0;j<4;j++)
        acc[i][j] = __builtin_amdgcn_mfma_f32_16x16x32_bf16(af[i], bfv[j], acc[i][j], 0,0,0);
    __syncthreads();
  }

  #pragma unroll
  for (int i=0;i<4;i++){
    #pragma unroll
    for (int j=0;j<4;j++){
      const int col = n0 + wc + j*16 + l15;
      const float bsv = bias[col];
      if (MODE == 3 && col >= 2048){
        // V branch: 4 consecutive s per lane -> packed b64 store
        const int n = col - 2048, h = n >> 6, fidx = n & 63;
        const int rowb = m0 + wr + i*16 + quad*4;
        const int b = rowb >> 11, s = rowb & 2047;
        float v0 = acc[i][j][0] + bsv, v1 = acc[i][j][1] + bsv;
        float v2 = acc[i][j][2] + bsv, v3 = acc[i][j][3] + bsv;
        unsigned lo = pk2(v0, v1), hi = pk2(v2, v3);
        uint2 pkd = make_uint2(lo, hi);
        *(uint2*)((unsigned short*)out2 + (size_t)(((b<<4) + h)*64 + fidx)*2048 + s) = pkd;
        continue;
      }
      #pragma unroll
      for (int r=0;r<4;r++){
        const int row = m0 + wr + i*16 + quad*4 + r;
        const float v = acc[i][j][r] + bsv;
        if (MODE == 1){
          ((float*)out0)[(size_t)row*N + col] = v;
        } else if (MODE == 2){
          const float gl = 0.5f*v*(1.0f + erff(v*0.70710678118654752f));
          ((unsigned short*)out0)[(size_t)row*N + col] = f2bs(gl);
        } else { // MODE 3: Q / K branches
          if (col < 1024){
            // fold 1/8 (head scale) and log2(e) (softmax uses exp2) into Q
            ((unsigned short*)out0)[(size_t)row*1024 + col] = f2bs(v*0.18033688011112042f);
          } else {
            ((unsigned short*)out1)[(size_t)row*1024 + (col-1024)] = f2bs(v);
          }
        }
      }
    }
  }
}

// ---------------- causal flash attention, S^T formulation, paired q-tiles ----------------
// Q [8192][1024] bf16 (pre-scaled by log2e/8), K [8192][1024] bf16,
// Vt [64][64][2048] bf16, O [8192][1024] bf16.
// Block = (pair p, bh): owns q-tiles qt_lo=p and qt_hi=31-p (64 rows each).
// One kv sweep kt=0..qt_hi; for kt<=qt_lo BOTH tiles consume the same staged
// K/V tile. Work per block = 33 tile-steps for every p -> perfectly balanced
// grid of 1024 blocks = 4/CU, all resident, no tail.
__global__ __launch_bounds__(256, 4) void attn(const unsigned short* __restrict__ Q,
                                               const unsigned short* __restrict__ Kg,
                                               const unsigned short* __restrict__ Vt,
                                               unsigned short* __restrict__ O){
  __shared__ __align__(16) unsigned short Ks[64*64];
  __shared__ __align__(16) unsigned short Vs[64*64];
  __shared__ __align__(16) unsigned short PT[4][16*68]; // per-wave P^T: row=q(l15), 64 kv, +4 pad

  const int qt_lo = blockIdx.x;        // 0..15
  const int qt_hi = 31 - qt_lo;        // 16..31
  const int bh = blockIdx.y;
  const int b = bh >> 4, h = bh & 15;
  const int tid = threadIdx.x, wave = tid >> 6, lane = tid & 63;
  const int quad = lane >> 4, l15 = lane & 15;

  // Q fragments for both tiles: rows = qt*64 + wave*16 + l15
  const size_t qbase = (size_t)((b<<11) + (wave<<4) + l15)*1024 + (h<<6);
  bf16x8 qf_hi[2], qf_lo[2];
  qf_hi[0] = *(const bf16x8*)(Q + qbase + (size_t)(qt_hi<<6)*1024 + quad*8);
  qf_hi[1] = *(const bf16x8*)(Q + qbase + (size_t)(qt_hi<<6)*1024 + 32 + quad*8);
  qf_lo[0] = *(const bf16x8*)(Q + qbase + (size_t)(qt_lo<<6)*1024 + quad*8);
  qf_lo[1] = *(const bf16x8*)(Q + qbase + (size_t)(qt_lo<<6)*1024 + 32 + quad*8);

  floatx4 oa_hi[4], oa_lo[4];    // oa[tn][r] = O^T[hd=tn*16+quad*4+r][q=l15]
  #pragma unroll
  for (int i=0;i<4;i++){ oa_hi[i] = (floatx4)0.0f; oa_lo[i] = (floatx4)0.0f; }
  float mi_hi = -3e38f, li_hi = 0.0f;
  float mi_lo = -3e38f, li_lo = 0.0f;

  const unsigned short* Kbh = Kg + ((size_t)(b<<11))*1024 + (h<<6);
  const unsigned short* Vbh = Vt + (size_t)bh*64*2048;
  unsigned short* Pw = &PT[wave][0];

  const int slot0 = wave*128 + lane;
  const int krow0 = slot0 >> 3, kc0 = (slot0 & 7) ^ (krow0 & 7);
  const int slot1 = slot0 + 64;
  const int krow1 = slot1 >> 3, kc1 = (slot1 & 7) ^ (krow1 & 7);

  // one tile-step: S^T = K.Q^T, online softmax, O^T += V^T.P^T
  auto tile_step = [&](const bf16x8* qf, floatx4* oa, float& mi, float& li, bool diag){
    floatx4 sa[4];
    #pragma unroll
    for (int tj=0;tj<4;tj++){
      sa[tj] = (floatx4)0.0f;
      #pragma unroll
      for (int ks=0;ks<2;ks++){
        const int n = tj*16 + l15;
        const int c = (ks*4 + quad) ^ (n & 7);
        const bf16x8 kf = *(const bf16x8*)(Ks + n*64 + c*8);
        sa[tj] = __builtin_amdgcn_mfma_f32_16x16x32_bf16(kf, qf[ks], sa[tj], 0,0,0);
      }
    }
    if (diag){
      const int qrow = (wave<<4) + l15;
      #pragma unroll
      for (int tj=0;tj<4;tj++)
        #pragma unroll
        for (int r=0;r<4;r++)
          if (tj*16 + quad*4 + r > qrow) sa[tj][r] = -1e30f;
    }
    float mx = fmaxf(fmaxf(fmaxf(sa[0][0],sa[0][1]),fmaxf(sa[0][2],sa[0][3])),
                     fmaxf(fmaxf(sa[1][0],sa[1][1]),fmaxf(sa[1][2],sa[1][3])));
    mx = fmaxf(mx, fmaxf(fmaxf(fmaxf(sa[2][0],sa[2][1]),fmaxf(sa[2][2],sa[2][3])),
                         fmaxf(fmaxf(sa[3][0],sa[3][1]),fmaxf(sa[3][2],sa[3][3]))));
    mx = fmaxf(mx, __shfl_xor(mx, 16, 64));
    mx = fmaxf(mx, __shfl_xor(mx, 32, 64));
    const float mn = fmaxf(mi, mx);
    const float al = __builtin_amdgcn_exp2f(mi - mn);
    float rs = 0.0f;
    #pragma unroll
    for (int tj=0;tj<4;tj++)
      #pragma unroll
      for (int r=0;r<4;r++){
        const float p = __builtin_amdgcn_exp2f(sa[tj][r] - mn);
        sa[tj][r] = p;
        rs += p;
      }
    rs += __shfl_xor(rs, 16, 64);
    rs += __shfl_xor(rs, 32, 64);
    li = li*al + rs;
    mi = mn;
    #pragma unroll
    for (int tn=0;tn<4;tn++) oa[tn] *= al;

    #pragma unroll
    for (int tj=0;tj<4;tj++){
      uint2 pkd = make_uint2(pk2(sa[tj][0], sa[tj][1]), pk2(sa[tj][2], sa[tj][3]));
      *(uint2*)(Pw + l15*68 + tj*16 + quad*4) = pkd;
    }
    #pragma unroll
    for (int ks2=0;ks2<2;ks2++){
      const bf16x8 pf = *(const bf16x8*)(Pw + l15*68 + ks2*32 + quad*8);
      #pragma unroll
      for (int tn=0;tn<4;tn++){
        const int n2 = tn*16 + l15;
        const int c = (ks2*4 + quad) ^ (n2 & 7);
        const bf16x8 vf = *(const bf16x8*)(Vs + n2*64 + c*8);
        oa[tn] = __builtin_amdgcn_mfma_f32_16x16x32_bf16(vf, pf, oa[tn], 0,0,0);
      }
    }
  };

  for (int kt = 0; kt <= qt_hi; ++kt){
    gl_lds16(Kbh + (size_t)((kt<<6) + krow0)*1024 + kc0*8, Ks + wave*1024);
    gl_lds16(Kbh + (size_t)((kt<<6) + krow1)*1024 + kc1*8, Ks + wave*1024 + 512);
    gl_lds16(Vbh + (size_t)krow0*2048 + (kt<<6) + kc0*8, Vs + wave*1024);
    gl_lds16(Vbh + (size_t)krow1*2048 + (kt<<6) + kc1*8, Vs + wave*1024 + 512);
    __syncthreads();

    tile_step(qf_hi, oa_hi, mi_hi, li_hi, kt == qt_hi);
    if (kt <= qt_lo)
      tile_step(qf_lo, oa_lo, mi_lo, li_lo, kt == qt_lo);

    __syncthreads();
  }

  // epilogue: both tiles; per lane 4 contiguous hd per tn -> packed b64 stores
  {
    const float inv = 1.0f / li_hi;
    unsigned short* Orow = O + (size_t)((b<<11) + (qt_hi<<6) + (wave<<4) + l15)*1024 + (h<<6);
    #pragma unroll
    for (int tn=0;tn<4;tn++){
      uint2 pkd = make_uint2(pk2(oa_hi[tn][0]*inv, oa_hi[tn][1]*inv),
                             pk2(oa_hi[tn][2]*inv, oa_hi[tn][3]*inv));
      *(uint2*)(Orow + tn*16 + quad*4) = pkd;
    }
  }
  {
    const float inv = 1.0f / li_lo;
    unsigned short* Orow = O + (size_t)((b<<11) + (qt_lo<<6) + (wave<<4) + l15)*1024 + (h<<6);
    #pragma unroll
    for (int tn=0;tn<4;tn++){
      uint2 pkd = make_uint2(pk2(oa_lo[tn][0]*inv, oa_lo[tn][1]*inv),
                             pk2(oa_lo[tn][2]*inv, oa_lo[tn][3]*inv));
      *(uint2*)(Orow + tn*16 + quad*4) = pkd;
    }
  }
}

// ---------------- residual + LayerNorm (one row per block) ----------------
__global__ __launch_bounds__(256) void ln_res(const float* __restrict__ a,
                                              const float* __restrict__ bsrc,
                                              const float* __restrict__ g,
                                              const float* __restrict__ be,
                                              float* __restrict__ of,
                                              unsigned short* __restrict__ ob){
  __shared__ float red1[4], red2[4];
  const int row = blockIdx.x, t = threadIdx.x;
  const int wave = t >> 6, lane = t & 63;
  const float4 va = *(const float4*)(a + (size_t)row*1024 + t*4);
  const float4 vb = *(const float4*)(bsrc + (size_t)row*1024 + t*4);
  float xs[4] = {va.x+vb.x, va.y+vb.y, va.z+vb.z, va.w+vb.w};
  float s = xs[0]+xs[1]+xs[2]+xs[3];
  #pragma unroll
  for (int d=1; d<64; d<<=1) s += __shfl_xor(s, d, 64);
  if (lane==0) red1[wave] = s;
  __syncthreads();
  const float mean = (red1[0]+red1[1]+red1[2]+red1[3]) * (1.0f/1024.0f);
  float vsum = 0.0f;
  #pragma unroll
  for (int i=0;i<4;i++){ const float d = xs[i]-mean; vsum += d*d; }
  #pragma unroll
  for (int d=1; d<64; d<<=1) vsum += __shfl_xor(vsum, d, 64);
  if (lane==0) red2[wave] = vsum;
  __syncthreads();
  const float var = (red2[0]+red2[1]+red2[2]+red2[3]) * (1.0f/1024.0f);
  const float rs = rsqrtf(var + 1e-5f);
  const float4 gg = *(const float4*)(g + t*4);
  const float4 bb = *(const float4*)(be + t*4);
  float y[4];
  y[0] = (xs[0]-mean)*rs*gg.x + bb.x;
  y[1] = (xs[1]-mean)*rs*gg.y + bb.y;
  y[2] = (xs[2]-mean)*rs*gg.z + bb.z;
  y[3] = (xs[3]-mean)*rs*gg.w + bb.w;
  if (of){
    float4 o4; o4.x=y[0]; o4.y=y[1]; o4.z=y[2]; o4.w=y[3];
    *(float4*)(of + (size_t)row*1024 + t*4) = o4;
  }
  if (ob){
    ushort4v u = { f2bs(y[0]), f2bs(y[1]), f2bs(y[2]), f2bs(y[3]) };
    *(ushort4v*)(ob + (size_t)row*1024 + t*4) = u;
  }
}

extern "C" void kernel_launch(void* const* d_in, const int* in_sizes, int n_in,
                              void* d_out, int out_size, void* d_ws, size_t ws_size,
                              hipStream_t stream){
  (void)in_sizes; (void)n_in; (void)out_size; (void)ws_size;
  const float* x  = (const float*)d_in[0];
  const float* wq = (const float*)d_in[1];
  const float* bq = (const float*)d_in[2];
  const float* wk = (const float*)d_in[3];
  const float* bk = (const float*)d_in[4];
  const float* wv = (const float*)d_in[5];
  const float* bv = (const float*)d_in[6];
  const float* wo = (const float*)d_in[7];
  const float* bo = (const float*)d_in[8];
  const float* w1 = (const float*)d_in[9];
  const float* b1 = (const float*)d_in[10];
  const float* w2 = (const float*)d_in[11];
  const float* b2 = (const float*)d_in[12];
  const float* g1 = (const float*)d_in[13];
  const float* be1= (const float*)d_in[14];
  const float* g2 = (const float*)d_in[15];
  const float* be2= (const float*)d_in[16];
  float* out = (float*)d_out;

  char* ws = (char*)d_ws;
  size_t off = 0;
  auto take = [&](size_t bytes)->char*{
    char* p = ws + off; off += (bytes + 255) & ~(size_t)255; return p;
  };
  unsigned short* Xb  = (unsigned short*)take(8192UL*1024*2);
  unsigned short* Qb  = (unsigned short*)take(8192UL*1024*2);
  unsigned short* Kb  = (unsigned short*)take(8192UL*1024*2);
  unsigned short* Vtb = (unsigned short*)take(8192UL*1024*2);
  unsigned short* Ob  = (unsigned short*)take(8192UL*1024*2);
  unsigned short* Midb= Qb;                    // alias: spans Qb..Ob (64 MB), dead by FFN1
  unsigned short* Wqkv= (unsigned short*)take(3072UL*1024*2);
  float*          Bqkv= (float*)take(3072UL*4);
  unsigned short* Wot = (unsigned short*)take(1024UL*1024*2);
  unsigned short* W1t = (unsigned short*)take(4096UL*1024*2);
  unsigned short* W2t = (unsigned short*)take(1024UL*4096*2);
  float*          C1  = (float*)take(8192UL*1024*4);
  float*          Ff  = C1;                    // alias: attn-proj dead after LN1
  float*          Hf  = (float*)take(8192UL*1024*4);
  unsigned short* Hb  = (unsigned short*)take(8192UL*1024*2);

  // 1. pack inputs/weights to bf16 MFMA layouts
  cvt_x<<<8192, 256, 0, stream>>>(x, Xb);
  pack_qkv<<<dim3(32,16,3), 256, 0, stream>>>(wq, wk, wv, bq, bk, bv, Wqkv, Bqkv);
  transpose_pack<<<dim3(16,32),  256, 0, stream>>>(wo, Wot, 1024, 1024);
  transpose_pack<<<dim3(64,32),  256, 0, stream>>>(w1, W1t, 1024, 4096);
  transpose_pack<<<dim3(16,128), 256, 0, stream>>>(w2, W2t, 4096, 1024);

  // 2. fused QKV projection (Q pre-scaled log2e/8, V stored transposed)
  gemm_bt<3><<<dim3(24,64), 256, 0, stream>>>(Xb, Wqkv, Bqkv, Qb, Kb, Vtb, 8192, 3072, 1024);

  // 3. causal flash attention (paired q-tiles, balanced grid)
  attn<<<dim3(16,64), 256, 0, stream>>>(Qb, Kb, Vtb, Ob);

  // 4. output projection (fp32) then residual + LN1 -> h (fp32 + bf16)
  gemm_bt<1><<<dim3(8,64), 256, 0, stream>>>(Ob, Wot, bo, C1, nullptr, nullptr, 8192, 1024, 1024);
  ln_res<<<8192, 256, 0, stream>>>(x, C1, g1, be1, Hf, Hb);

  // 5. FFN: gelu(h@w1+b1)@w2+b2, then residual + LN2 -> out
  gemm_bt<2><<<dim3(32,64), 256, 0, stream>>>(Hb, W1t, b1, Midb, nullptr, nullptr, 8192, 4096, 1024);
  gemm_bt<1><<<dim3(8,64), 256, 0, stream>>>(Midb, W2t, b2, Ff, nullptr, nullptr, 8192, 1024, 4096);
  ln_res<<<8192, 256, 0, stream>>>(Hf, Ff, g2, be2, out, nullptr);
}

// Round 5
// 602.012 us; speedup vs baseline: 1.6564x; 1.0674x over previous
//
#include <hip/hip_runtime.h>
#include <hip/hip_bf16.h>
#include <math.h>

typedef __bf16 bf16x8 __attribute__((ext_vector_type(8)));
typedef float floatx4 __attribute__((ext_vector_type(4)));
typedef unsigned short ushort8 __attribute__((ext_vector_type(8)));
typedef unsigned short ushort4v __attribute__((ext_vector_type(4)));

__device__ __forceinline__ unsigned short f2bs(float f){
  union { float f; unsigned u; } v; v.f = f;
  unsigned r = v.u + 0x7fffu + ((v.u >> 16) & 1u);
  return (unsigned short)(r >> 16);
}

// packed f32x2 -> bf16x2 (RNE)
__device__ __forceinline__ unsigned pk2(float a, float b){
  union { __hip_bfloat162 h; unsigned u; } cv;
  cv.h = __float22bfloat162_rn(make_float2(a, b));
  return cv.u;
}

__device__ __forceinline__ void gl_lds16(const void* g, void* l){
  __builtin_amdgcn_global_load_lds(
      (const __attribute__((address_space(1))) void*)g,
      (__attribute__((address_space(3))) void*)l,
      16, 0, 0);
}

// ---------------- elementwise convert x -> bf16 ----------------
__global__ __launch_bounds__(256) void cvt_x(const float* __restrict__ x,
                                             unsigned short* __restrict__ o){
  const int i = (blockIdx.x*256 + threadIdx.x)*4;
  const float4 v = *(const float4*)(x + i);
  ushort4v u = { f2bs(v.x), f2bs(v.y), f2bs(v.z), f2bs(v.w) };
  *(ushort4v*)(o + i) = u;
}

// ---------------- generic fp32 [R][C] -> bf16 [C][R] transpose ----------------
__global__ __launch_bounds__(256) void transpose_pack(const float* __restrict__ src,
                                                      unsigned short* __restrict__ dst,
                                                      int R, int C){
  __shared__ float tile[32][65];
  const int r0 = blockIdx.y*32, c0 = blockIdx.x*64;
  const int t = threadIdx.x;
  {
    const int r = t >> 3, cc = (t & 7)*8;
    const float* p = src + (size_t)(r0+r)*C + c0 + cc;
    const float4 v0 = *(const float4*)p;
    const float4 v1 = *(const float4*)(p+4);
    tile[r][cc+0]=v0.x; tile[r][cc+1]=v0.y; tile[r][cc+2]=v0.z; tile[r][cc+3]=v0.w;
    tile[r][cc+4]=v1.x; tile[r][cc+5]=v1.y; tile[r][cc+6]=v1.z; tile[r][cc+7]=v1.w;
  }
  __syncthreads();
  const int f = t >> 2, rr = (t & 3)*8;
  ushort8 u;
  #pragma unroll
  for (int j=0;j<8;j++) u[j] = f2bs(tile[rr+j][f]);
  *(ushort8*)(dst + (size_t)(c0+f)*R + r0 + rr) = u;
}

// ---------------- pack wq/wk/wv [H,D,HD] -> Wqkv_t [3072][1024] bf16 + bias ----------------
__global__ __launch_bounds__(256) void pack_qkv(const float* __restrict__ wq,
                                                const float* __restrict__ wk,
                                                const float* __restrict__ wv,
                                                const float* __restrict__ bq,
                                                const float* __restrict__ bk,
                                                const float* __restrict__ bv,
                                                unsigned short* __restrict__ Wt,
                                                float* __restrict__ Bc){
  __shared__ float tile[32][65];
  const int dt = blockIdx.x, h = blockIdx.y, sel = blockIdx.z;
  const float* src = (sel==0 ? wq : (sel==1 ? wk : wv)) + (size_t)h*65536;
  const int t = threadIdx.x, d0 = dt*32;
  {
    const int r = t >> 3, cc = (t & 7)*8;
    const float* p = src + (size_t)(d0+r)*64 + cc;
    const float4 v0 = *(const float4*)p;
    const float4 v1 = *(const float4*)(p+4);
    tile[r][cc+0]=v0.x; tile[r][cc+1]=v0.y; tile[r][cc+2]=v0.z; tile[r][cc+3]=v0.w;
    tile[r][cc+4]=v1.x; tile[r][cc+5]=v1.y; tile[r][cc+6]=v1.z; tile[r][cc+7]=v1.w;
  }
  __syncthreads();
  const int f = t >> 2, rr = (t & 3)*8;
  ushort8 u;
  #pragma unroll
  for (int j=0;j<8;j++) u[j] = f2bs(tile[rr+j][f]);
  const size_t n = (size_t)sel*1024 + h*64 + f;
  *(ushort8*)(Wt + n*1024 + d0 + rr) = u;
  if (dt==0 && t<64){
    const float* bs = (sel==0 ? bq : (sel==1 ? bk : bv)) + h*64;
    Bc[sel*1024 + h*64 + t] = bs[t];
  }
}

// ---------------- bf16 GEMM, BK=64, swizzled LDS, XCD-aware blocks ----------------
// C[M,N] = A[M,K] * Bt[N,K]^T + bias.  M/128 must be 64 (true for all uses).
// 1-D grid, lin -> (xcd = lin&7) owns m-tiles [xcd*8, xcd*8+8); n streams.
// LDS rows are 64 shorts (128 B = full bank wrap); 16-B chunks XOR-swizzled
// by row&7 -> ds_read_b128 fragment reads are 2-way (free). Staging via
// global_load_lds width=16, lane-linear LDS, swizzle applied to the GLOBAL
// chunk (wave-uniform-base constraint).
// MODE 1: fp32 out0.  MODE 2: tanh-gelu -> bf16 out0.  MODE 3: fused QKV.
template<int MODE>
__global__ __launch_bounds__(256) void gemm_bt(const unsigned short* __restrict__ A,
                                               const unsigned short* __restrict__ Bt,
                                               const float* __restrict__ bias,
                                               void* __restrict__ out0,
                                               void* __restrict__ out1,
                                               void* __restrict__ out2,
                                               int M, int N, int K){
  __shared__ __align__(16) unsigned short As[128*64];
  __shared__ __align__(16) unsigned short Bs[128*64];
  const int tid = threadIdx.x;
  const int wave = tid >> 6, lane = tid & 63;
  const int quad = lane >> 4, l15 = lane & 15;
  const int lin = blockIdx.x;
  const int xcd = lin & 7, rest = lin >> 3;
  const int mloc = rest & 7, nt = rest >> 3;
  const int m0 = (xcd*8 + mloc) << 7, n0 = nt << 7;
  const int wr = (wave >> 1) << 6, wc = (wave & 1) << 6;

  floatx4 acc[4][4];
  #pragma unroll
  for (int i=0;i<4;i++)
    #pragma unroll
    for (int j=0;j<4;j++) acc[i][j] = (floatx4)0.0f;

  // staging descriptors: 4 rounds x (1 A-chunk + 1 B-chunk) per lane
  const unsigned short* gA[4];
  const unsigned short* gB[4];
  int ldsOff[4];
  #pragma unroll
  for (int r2=0;r2<4;r2++){
    const int slot = r2*256 + wave*64 + lane;   // lane-linear LDS order
    const int row = slot >> 3, ch = slot & 7;
    const int col = (ch ^ (row & 7))*8;         // swizzle on global side
    gA[r2] = A  + (size_t)(m0 + row)*K + col;
    gB[r2] = Bt + (size_t)(n0 + row)*K + col;
    ldsOff[r2] = slot*8;
  }
  const int cs0 = (quad ^ (l15 & 7))*8;         // ks=0 fragment chunk
  const int cs1 = ((4 + quad) ^ (l15 & 7))*8;   // ks=1 fragment chunk

  for (int k0 = 0; k0 < K; k0 += 64){
    #pragma unroll
    for (int r2=0;r2<4;r2++){
      gl_lds16(gA[r2] + k0, As + ldsOff[r2]);
      gl_lds16(gB[r2] + k0, Bs + ldsOff[r2]);
    }
    __syncthreads();
    #pragma unroll
    for (int ks=0;ks<2;ks++){
      const int cs = ks ? cs1 : cs0;
      bf16x8 af[4], bfv[4];
      #pragma unroll
      for (int t=0;t<4;t++){
        af[t]  = *(const bf16x8*)(As + (wr + t*16 + l15)*64 + cs);
        bfv[t] = *(const bf16x8*)(Bs + (wc + t*16 + l15)*64 + cs);
      }
      #pragma unroll
      for (int i=0;i<4;i++)
        #pragma unroll
        for (int j=0;j<4;j++)
          acc[i][j] = __builtin_amdgcn_mfma_f32_16x16x32_bf16(af[i], bfv[j], acc[i][j], 0,0,0);
    }
    __syncthreads();
  }

  #pragma unroll
  for (int i=0;i<4;i++){
    #pragma unroll
    for (int j=0;j<4;j++){
      const int col = n0 + wc + j*16 + l15;
      const float bsv = bias[col];
      if (MODE == 3 && col >= 2048){
        // V branch: 4 consecutive s per lane -> packed b64 store
        const int n = col - 2048, h = n >> 6, fidx = n & 63;
        const int rowb = m0 + wr + i*16 + quad*4;
        const int b = rowb >> 11, s = rowb & 2047;
        float v0 = acc[i][j][0] + bsv, v1 = acc[i][j][1] + bsv;
        float v2 = acc[i][j][2] + bsv, v3 = acc[i][j][3] + bsv;
        uint2 pkd = make_uint2(pk2(v0, v1), pk2(v2, v3));
        *(uint2*)((unsigned short*)out2 + (size_t)(((b<<4) + h)*64 + fidx)*2048 + s) = pkd;
        continue;
      }
      #pragma unroll
      for (int r=0;r<4;r++){
        const int row = m0 + wr + i*16 + quad*4 + r;
        const float v = acc[i][j][r] + bsv;
        if (MODE == 1){
          ((float*)out0)[(size_t)row*N + col] = v;
        } else if (MODE == 2){
          // tanh-approx gelu (max abs err ~3e-4, well under bf16 noise)
          const float u = 0.7978845608f*v*(1.0f + 0.044715f*v*v);
          const float e = __builtin_amdgcn_exp2f(u * 2.885390082f);  // exp(2u)
          const float th = 1.0f - 2.0f/(1.0f + e);
          const float gl = 0.5f*v*(1.0f + th);
          ((unsigned short*)out0)[(size_t)row*N + col] = f2bs(gl);
        } else { // MODE 3: Q / K branches
          if (col < 1024){
            // fold 1/8 (head scale) and log2(e) (softmax uses exp2) into Q
            ((unsigned short*)out0)[(size_t)row*1024 + col] = f2bs(v*0.18033688011112042f);
          } else {
            ((unsigned short*)out1)[(size_t)row*1024 + (col-1024)] = f2bs(v);
          }
        }
      }
    }
  }
}

// ---------------- causal flash attention, S^T formulation, paired q-tiles ----------------
__global__ __launch_bounds__(256, 4) void attn(const unsigned short* __restrict__ Q,
                                               const unsigned short* __restrict__ Kg,
                                               const unsigned short* __restrict__ Vt,
                                               unsigned short* __restrict__ O){
  __shared__ __align__(16) unsigned short Ks[64*64];
  __shared__ __align__(16) unsigned short Vs[64*64];
  __shared__ __align__(16) unsigned short PT[4][16*68];

  const int qt_lo = blockIdx.x;        // 0..15
  const int qt_hi = 31 - qt_lo;        // 16..31
  const int bh = blockIdx.y;
  const int b = bh >> 4, h = bh & 15;
  const int tid = threadIdx.x, wave = tid >> 6, lane = tid & 63;
  const int quad = lane >> 4, l15 = lane & 15;

  const size_t qbase = (size_t)((b<<11) + (wave<<4) + l15)*1024 + (h<<6);
  bf16x8 qf_hi[2], qf_lo[2];
  qf_hi[0] = *(const bf16x8*)(Q + qbase + (size_t)(qt_hi<<6)*1024 + quad*8);
  qf_hi[1] = *(const bf16x8*)(Q + qbase + (size_t)(qt_hi<<6)*1024 + 32 + quad*8);
  qf_lo[0] = *(const bf16x8*)(Q + qbase + (size_t)(qt_lo<<6)*1024 + quad*8);
  qf_lo[1] = *(const bf16x8*)(Q + qbase + (size_t)(qt_lo<<6)*1024 + 32 + quad*8);

  floatx4 oa_hi[4], oa_lo[4];
  #pragma unroll
  for (int i=0;i<4;i++){ oa_hi[i] = (floatx4)0.0f; oa_lo[i] = (floatx4)0.0f; }
  float mi_hi = -3e38f, li_hi = 0.0f;
  float mi_lo = -3e38f, li_lo = 0.0f;

  const unsigned short* Kbh = Kg + ((size_t)(b<<11))*1024 + (h<<6);
  const unsigned short* Vbh = Vt + (size_t)bh*64*2048;
  unsigned short* Pw = &PT[wave][0];

  const int slot0 = wave*128 + lane;
  const int krow0 = slot0 >> 3, kc0 = (slot0 & 7) ^ (krow0 & 7);
  const int slot1 = slot0 + 64;
  const int krow1 = slot1 >> 3, kc1 = (slot1 & 7) ^ (krow1 & 7);

  auto tile_step = [&](const bf16x8* qf, floatx4* oa, float& mi, float& li, bool diag){
    floatx4 sa[4];
    #pragma unroll
    for (int tj=0;tj<4;tj++){
      sa[tj] = (floatx4)0.0f;
      #pragma unroll
      for (int ks=0;ks<2;ks++){
        const int n = tj*16 + l15;
        const int c = (ks*4 + quad) ^ (n & 7);
        const bf16x8 kf = *(const bf16x8*)(Ks + n*64 + c*8);
        sa[tj] = __builtin_amdgcn_mfma_f32_16x16x32_bf16(kf, qf[ks], sa[tj], 0,0,0);
      }
    }
    if (diag){
      const int qrow = (wave<<4) + l15;
      #pragma unroll
      for (int tj=0;tj<4;tj++)
        #pragma unroll
        for (int r=0;r<4;r++)
          if (tj*16 + quad*4 + r > qrow) sa[tj][r] = -1e30f;
    }
    float mx = fmaxf(fmaxf(fmaxf(sa[0][0],sa[0][1]),fmaxf(sa[0][2],sa[0][3])),
                     fmaxf(fmaxf(sa[1][0],sa[1][1]),fmaxf(sa[1][2],sa[1][3])));
    mx = fmaxf(mx, fmaxf(fmaxf(fmaxf(sa[2][0],sa[2][1]),fmaxf(sa[2][2],sa[2][3])),
                         fmaxf(fmaxf(sa[3][0],sa[3][1]),fmaxf(sa[3][2],sa[3][3]))));
    mx = fmaxf(mx, __shfl_xor(mx, 16, 64));
    mx = fmaxf(mx, __shfl_xor(mx, 32, 64));
    const float mn = fmaxf(mi, mx);
    const float al = __builtin_amdgcn_exp2f(mi - mn);
    float rs = 0.0f;
    #pragma unroll
    for (int tj=0;tj<4;tj++)
      #pragma unroll
      for (int r=0;r<4;r++){
        const float p = __builtin_amdgcn_exp2f(sa[tj][r] - mn);
        sa[tj][r] = p;
        rs += p;
      }
    rs += __shfl_xor(rs, 16, 64);
    rs += __shfl_xor(rs, 32, 64);
    li = li*al + rs;
    mi = mn;
    #pragma unroll
    for (int tn=0;tn<4;tn++) oa[tn] *= al;

    #pragma unroll
    for (int tj=0;tj<4;tj++){
      uint2 pkd = make_uint2(pk2(sa[tj][0], sa[tj][1]), pk2(sa[tj][2], sa[tj][3]));
      *(uint2*)(Pw + l15*68 + tj*16 + quad*4) = pkd;
    }
    #pragma unroll
    for (int ks2=0;ks2<2;ks2++){
      const bf16x8 pf = *(const bf16x8*)(Pw + l15*68 + ks2*32 + quad*8);
      #pragma unroll
      for (int tn=0;tn<4;tn++){
        const int n2 = tn*16 + l15;
        const int c = (ks2*4 + quad) ^ (n2 & 7);
        const bf16x8 vf = *(const bf16x8*)(Vs + n2*64 + c*8);
        oa[tn] = __builtin_amdgcn_mfma_f32_16x16x32_bf16(vf, pf, oa[tn], 0,0,0);
      }
    }
  };

  for (int kt = 0; kt <= qt_hi; ++kt){
    gl_lds16(Kbh + (size_t)((kt<<6) + krow0)*1024 + kc0*8, Ks + wave*1024);
    gl_lds16(Kbh + (size_t)((kt<<6) + krow1)*1024 + kc1*8, Ks + wave*1024 + 512);
    gl_lds16(Vbh + (size_t)krow0*2048 + (kt<<6) + kc0*8, Vs + wave*1024);
    gl_lds16(Vbh + (size_t)krow1*2048 + (kt<<6) + kc1*8, Vs + wave*1024 + 512);
    __syncthreads();

    tile_step(qf_hi, oa_hi, mi_hi, li_hi, kt == qt_hi);
    if (kt <= qt_lo)
      tile_step(qf_lo, oa_lo, mi_lo, li_lo, kt == qt_lo);

    __syncthreads();
  }

  {
    const float inv = 1.0f / li_hi;
    unsigned short* Orow = O + (size_t)((b<<11) + (qt_hi<<6) + (wave<<4) + l15)*1024 + (h<<6);
    #pragma unroll
    for (int tn=0;tn<4;tn++){
      uint2 pkd = make_uint2(pk2(oa_hi[tn][0]*inv, oa_hi[tn][1]*inv),
                             pk2(oa_hi[tn][2]*inv, oa_hi[tn][3]*inv));
      *(uint2*)(Orow + tn*16 + quad*4) = pkd;
    }
  }
  {
    const float inv = 1.0f / li_lo;
    unsigned short* Orow = O + (size_t)((b<<11) + (qt_lo<<6) + (wave<<4) + l15)*1024 + (h<<6);
    #pragma unroll
    for (int tn=0;tn<4;tn++){
      uint2 pkd = make_uint2(pk2(oa_lo[tn][0]*inv, oa_lo[tn][1]*inv),
                             pk2(oa_lo[tn][2]*inv, oa_lo[tn][3]*inv));
      *(uint2*)(Orow + tn*16 + quad*4) = pkd;
    }
  }
}

// ---------------- residual + LayerNorm (one row per block) ----------------
__global__ __launch_bounds__(256) void ln_res(const float* __restrict__ a,
                                              const float* __restrict__ bsrc,
                                              const float* __restrict__ g,
                                              const float* __restrict__ be,
                                              float* __restrict__ of,
                                              unsigned short* __restrict__ ob){
  __shared__ float red1[4], red2[4];
  const int row = blockIdx.x, t = threadIdx.x;
  const int wave = t >> 6, lane = t & 63;
  const float4 va = *(const float4*)(a + (size_t)row*1024 + t*4);
  const float4 vb = *(const float4*)(bsrc + (size_t)row*1024 + t*4);
  float xs[4] = {va.x+vb.x, va.y+vb.y, va.z+vb.z, va.w+vb.w};
  float s = xs[0]+xs[1]+xs[2]+xs[3];
  #pragma unroll
  for (int d=1; d<64; d<<=1) s += __shfl_xor(s, d, 64);
  if (lane==0) red1[wave] = s;
  __syncthreads();
  const float mean = (red1[0]+red1[1]+red1[2]+red1[3]) * (1.0f/1024.0f);
  float vsum = 0.0f;
  #pragma unroll
  for (int i=0;i<4;i++){ const float d = xs[i]-mean; vsum += d*d; }
  #pragma unroll
  for (int d=1; d<64; d<<=1) vsum += __shfl_xor(vsum, d, 64);
  if (lane==0) red2[wave] = vsum;
  __syncthreads();
  const float var = (red2[0]+red2[1]+red2[2]+red2[3]) * (1.0f/1024.0f);
  const float rs = rsqrtf(var + 1e-5f);
  const float4 gg = *(const float4*)(g + t*4);
  const float4 bb = *(const float4*)(be + t*4);
  float y[4];
  y[0] = (xs[0]-mean)*rs*gg.x + bb.x;
  y[1] = (xs[1]-mean)*rs*gg.y + bb.y;
  y[2] = (xs[2]-mean)*rs*gg.z + bb.z;
  y[3] = (xs[3]-mean)*rs*gg.w + bb.w;
  if (of){
    float4 o4; o4.x=y[0]; o4.y=y[1]; o4.z=y[2]; o4.w=y[3];
    *(float4*)(of + (size_t)row*1024 + t*4) = o4;
  }
  if (ob){
    ushort4v u = { f2bs(y[0]), f2bs(y[1]), f2bs(y[2]), f2bs(y[3]) };
    *(ushort4v*)(ob + (size_t)row*1024 + t*4) = u;
  }
}

extern "C" void kernel_launch(void* const* d_in, const int* in_sizes, int n_in,
                              void* d_out, int out_size, void* d_ws, size_t ws_size,
                              hipStream_t stream){
  (void)in_sizes; (void)n_in; (void)out_size; (void)ws_size;
  const float* x  = (const float*)d_in[0];
  const float* wq = (const float*)d_in[1];
  const float* bq = (const float*)d_in[2];
  const float* wk = (const float*)d_in[3];
  const float* bk = (const float*)d_in[4];
  const float* wv = (const float*)d_in[5];
  const float* bv = (const float*)d_in[6];
  const float* wo = (const float*)d_in[7];
  const float* bo = (const float*)d_in[8];
  const float* w1 = (const float*)d_in[9];
  const float* b1 = (const float*)d_in[10];
  const float* w2 = (const float*)d_in[11];
  const float* b2 = (const float*)d_in[12];
  const float* g1 = (const float*)d_in[13];
  const float* be1= (const float*)d_in[14];
  const float* g2 = (const float*)d_in[15];
  const float* be2= (const float*)d_in[16];
  float* out = (float*)d_out;

  char* ws = (char*)d_ws;
  size_t off = 0;
  auto take = [&](size_t bytes)->char*{
    char* p = ws + off; off += (bytes + 255) & ~(size_t)255; return p;
  };
  unsigned short* Xb  = (unsigned short*)take(8192UL*1024*2);
  unsigned short* Qb  = (unsigned short*)take(8192UL*1024*2);
  unsigned short* Kb  = (unsigned short*)take(8192UL*1024*2);
  unsigned short* Vtb = (unsigned short*)take(8192UL*1024*2);
  unsigned short* Ob  = (unsigned short*)take(8192UL*1024*2);
  unsigned short* Midb= Qb;                    // alias: spans Qb..Ob (64 MB), dead by FFN1
  unsigned short* Wqkv= (unsigned short*)take(3072UL*1024*2);
  float*          Bqkv= (float*)take(3072UL*4);
  unsigned short* Wot = (unsigned short*)take(1024UL*1024*2);
  unsigned short* W1t = (unsigned short*)take(4096UL*1024*2);
  unsigned short* W2t = (unsigned short*)take(1024UL*4096*2);
  float*          C1  = (float*)take(8192UL*1024*4);
  float*          Ff  = C1;                    // alias: attn-proj dead after LN1
  float*          Hf  = (float*)take(8192UL*1024*4);
  unsigned short* Hb  = (unsigned short*)take(8192UL*1024*2);

  // 1. pack inputs/weights to bf16 MFMA layouts
  cvt_x<<<8192, 256, 0, stream>>>(x, Xb);
  pack_qkv<<<dim3(32,16,3), 256, 0, stream>>>(wq, wk, wv, bq, bk, bv, Wqkv, Bqkv);
  transpose_pack<<<dim3(16,32),  256, 0, stream>>>(wo, Wot, 1024, 1024);
  transpose_pack<<<dim3(64,32),  256, 0, stream>>>(w1, W1t, 1024, 4096);
  transpose_pack<<<dim3(16,128), 256, 0, stream>>>(w2, W2t, 4096, 1024);

  // 2. fused QKV projection (Q pre-scaled log2e/8, V stored transposed)
  gemm_bt<3><<<64*24, 256, 0, stream>>>(Xb, Wqkv, Bqkv, Qb, Kb, Vtb, 8192, 3072, 1024);

  // 3. causal flash attention (paired q-tiles, balanced grid)
  attn<<<dim3(16,64), 256, 0, stream>>>(Qb, Kb, Vtb, Ob);

  // 4. output projection (fp32) then residual + LN1 -> h (fp32 + bf16)
  gemm_bt<1><<<64*8, 256, 0, stream>>>(Ob, Wot, bo, C1, nullptr, nullptr, 8192, 1024, 1024);
  ln_res<<<8192, 256, 0, stream>>>(x, C1, g1, be1, Hf, Hb);

  // 5. FFN: gelu(h@w1+b1)@w2+b2, then residual + LN2 -> out
  gemm_bt<2><<<64*32, 256, 0, stream>>>(Hb, W1t, b1, Midb, nullptr, nullptr, 8192, 4096, 1024);
  gemm_bt<1><<<64*8, 256, 0, stream>>>(Midb, W2t, b2, Ff, nullptr, nullptr, 8192, 1024, 4096);
  ln_res<<<8192, 256, 0, stream>>>(Hf, Ff, g2, be2, out, nullptr);
}